// Round 4
// baseline (374.017 us; speedup 1.0000x reference)
//
#include <hip/hip_runtime.h>
#include <hip/hip_bf16.h>

// out[b,j] = sum_{i,k} coef[j,i,k] * tanh(x[b,i])^k
// B=8192, IN=1024, OUT=1024, ORDER=7.
// k=0 plane -> per-j bias (computed in prep, added in gemm epilogue).
// GEMM: M=8192, N=1024, K=IN*7=7168, bf16 MFMA.
//
// Round 12:
//  * gemm_bt: B no longer staged in LDS. Each block's per-tile B-slice is
//    32 KB and L2/L3-resident (whole B = 14.7 MB), so B fragments are read
//    global->VGPR (L2 ~200cy), prefetched at tile top where they hide under
//    the A-stage vmcnt drain. LDS/block 64->32 KB => 3 anti-phased blocks/CU
//    (launch_bounds(256,3)); stage drain now covered by 2 computing blocks.
//    LDS-read traffic halves (B moved to vmem pipe). Accumulation order is
//    bitwise-identical to round 11.
//  * prep: plane-major (K-index = (k-1)*1024 + i), LDS-free, coalesced
//    16B/lane stores; at BW floor (~35-40us of 199MB). Unchanged.

#define KT 7168
#define KFULL 8192

// gemm tile
#define BM 128
#define BN 128
#define BK 128

typedef short bf16x8 __attribute__((ext_vector_type(8)));
typedef short bf16x4 __attribute__((ext_vector_type(4)));
typedef float f32x4  __attribute__((ext_vector_type(4)));

__device__ __forceinline__ unsigned short f2bf(float f) {
    union { __hip_bfloat16 h; unsigned short u; } v;
    v.h = __float2bfloat16(f);   // RTE
    return v.u;
}

__device__ __forceinline__ void gload_lds16(const void* gp, void* lp) {
    __builtin_amdgcn_global_load_lds(
        (const __attribute__((address_space(1))) void*)gp,
        (__attribute__((address_space(3))) void*)lp, 16, 0, 0);
}

// ---- pass 1: prep (plane-major, LDS-free) ----
#define CVT_BLOCKS  512
#define TANH_BLOCKS 4096

__global__ __launch_bounds__(256)
void prep(const float* __restrict__ x, const float* __restrict__ trp,
          const float* __restrict__ coef, unsigned short* __restrict__ coef_bf,
          unsigned short* __restrict__ A, float* __restrict__ bias) {
    __shared__ float redbuf[4];

    const int t   = threadIdx.x;
    const int blk = blockIdx.x;
    const int rl  = t >> 7;        // row_local 0/1
    const int ig  = t & 127;       // i-group (8 i's each)

    if (blk < CVT_BLOCKS) {
        // ---- coef conversion: row j, k=1..7 -> planes 0..6; k=0 -> bias ----
        const int j = blk * 2 + rl;
        const float* src = coef + (size_t)j * KFULL + ig * 64;
        float k0sum = 0.f;
        bf16x8 pl[7];
        #pragma unroll
        for (int i = 0; i < 8; ++i) {
            const float4 f0 = *(const float4*)(src + i * 8);
            const float4 f1 = *(const float4*)(src + i * 8 + 4);
            k0sum += f0.x;
            pl[0][i] = (short)f2bf(f0.y); pl[1][i] = (short)f2bf(f0.z);
            pl[2][i] = (short)f2bf(f0.w); pl[3][i] = (short)f2bf(f1.x);
            pl[4][i] = (short)f2bf(f1.y); pl[5][i] = (short)f2bf(f1.z);
            pl[6][i] = (short)f2bf(f1.w);
        }
        #pragma unroll
        for (int off = 32; off > 0; off >>= 1) k0sum += __shfl_down(k0sum, off, 64);
        if ((t & 63) == 0) redbuf[t >> 6] = k0sum;
        __syncthreads();
        if (t == 0)   bias[j] = redbuf[0] + redbuf[1];
        if (t == 128) bias[j] = redbuf[2] + redbuf[3];

        unsigned short* dst = coef_bf + (size_t)j * KT + ig * 8;
        #pragma unroll
        for (int p = 0; p < 7; ++p)
            *(bf16x8*)(dst + p * 1024) = pl[p];   // coalesced: 16B/lane contiguous
    } else {
        // ---- tanh powers: row bb, plane p holds tanh(x)^(p+1) ----
        const int bb = (blk - CVT_BLOCKS) * 2 + rl;
        const float tr = trp[0];
        const float* xp = x + (size_t)bb * 1024 + ig * 8;
        const float4 x0 = *(const float4*)xp;
        const float4 x1 = *(const float4*)(xp + 4);
        const float xs[8] = {x0.x, x0.y, x0.z, x0.w, x1.x, x1.y, x1.z, x1.w};
        bf16x8 pl[7];
        #pragma unroll
        for (int i = 0; i < 8; ++i) {
            const float e  = __expf(2.0f * tr * xs[i]);
            const float tt = 1.0f - 2.0f * __builtin_amdgcn_rcpf(e + 1.0f);  // tanh(tr*x)
            float pw = tt;
            #pragma unroll
            for (int p = 0; p < 7; ++p) { pl[p][i] = (short)f2bf(pw); pw *= tt; }
        }
        unsigned short* dst = A + (size_t)bb * KT + ig * 8;
        #pragma unroll
        for (int p = 0; p < 7; ++p)
            *(bf16x8*)(dst + p * 1024) = pl[p];   // coalesced: 16B/lane contiguous
    }
}

// ---- pass 2: NT GEMM (K=7168), A in LDS (XOR-swizzled), B global->VGPR ----
// A swizzle (16 chunks/row): slot s of row m holds global chunk s^(m&15).
__global__ __launch_bounds__(256, 3)
void gemm_bt(const unsigned short* __restrict__ A, const unsigned short* __restrict__ Bt,
             const float* __restrict__ bias, float* __restrict__ out)
{
    __shared__ unsigned short As[BM * BK];   // 32 KB -> 3 blocks/CU (VGPR-capped)

    const int t    = threadIdx.x;
    const int m0   = blockIdx.x * BM;   // x = m-tile: A-sharers land on same XCD
    const int n0   = blockIdx.y * BN;
    const int w    = t >> 6;
    const int lane = t & 63;
    const int wm   = (w >> 1) * 64;
    const int wn   = (w & 1) * 64;
    const int lrow = lane & 15;

    // A staging: thread t covers row srow + r*16 (r=0..7); fetches swizzled
    // chunk schunk = (t&15)^srow so LDS slot s of row m holds chunk s^(m&15).
    const int srow   = t >> 4;           // 0..15
    const int schunk = (t & 15) ^ srow;
    const int wbase  = w * 512;          // ushort units; +lane*16B applied by HW

    const size_t abase = (size_t)(m0 + srow) * KT + schunk * 8;

    // B fragment bases: row = n0 + wn + j*16 + lrow, quad column offset.
    const unsigned short* bG[4];
    #pragma unroll
    for (int j = 0; j < 4; ++j)
        bG[j] = Bt + (size_t)(n0 + wn + j * 16 + lrow) * KT + (lane >> 4) * 8;

    f32x4 acc[4][4];
    #pragma unroll
    for (int i = 0; i < 4; i++)
        #pragma unroll
        for (int j = 0; j < 4; j++)
            acc[i][j] = (f32x4){0.f, 0.f, 0.f, 0.f};

    for (int k0 = 0; k0 < KT; k0 += BK) {
        // B frags for kk=0,32: issued BEFORE the A stage; they complete under
        // the barrier's vmcnt drain at zero marginal cost.
        bf16x8 b01[2][4];
        #pragma unroll
        for (int j = 0; j < 4; ++j) {
            b01[0][j] = *(const bf16x8*)(bG[j] + k0);
            b01[1][j] = *(const bf16x8*)(bG[j] + k0 + 32);
        }

        #pragma unroll
        for (int r = 0; r < 8; ++r)
            gload_lds16(A + abase + (size_t)r * 16 * KT + k0, &As[r * 2048 + wbase]);

        __syncthreads();

        // B frags for kk=64,96: L2-hit latency hides under kk=0/32 ds_read+MFMA.
        bf16x8 b23[2][4];
        #pragma unroll
        for (int j = 0; j < 4; ++j) {
            b23[0][j] = *(const bf16x8*)(bG[j] + k0 + 64);
            b23[1][j] = *(const bf16x8*)(bG[j] + k0 + 96);
        }

        #pragma unroll
        for (int kk = 0; kk < BK; kk += 32) {
            // A: global chunk c = kk/8 + quad; stored at slot c^(m&15), m&15 == lane&15
            const int soff = ((((kk >> 3) + (lane >> 4)) ^ (lane & 15)) * 8);
            bf16x8 a[4];
            #pragma unroll
            for (int i = 0; i < 4; i++)
                a[i] = *(const bf16x8*)&As[(wm + i * 16 + lrow) * BK + soff];
            const bf16x8* bq = (kk < 64) ? b01[(kk >> 5) & 1] : b23[(kk >> 5) & 1];
            #pragma unroll
            for (int i = 0; i < 4; i++)
                #pragma unroll
                for (int j = 0; j < 4; j++)
                    acc[i][j] = __builtin_amdgcn_mfma_f32_16x16x32_bf16(a[i], bq[j], acc[i][j], 0, 0, 0);
        }

        __syncthreads();
    }

    const int crow = (lane >> 4) * 4;
    const int ccol = lane & 15;
    #pragma unroll
    for (int j = 0; j < 4; j++) {
        const int n = n0 + wn + j * 16 + ccol;
        const float bv = bias[n];
        #pragma unroll
        for (int i = 0; i < 4; i++) {
            const int m = m0 + wm + i * 16 + crow;
            #pragma unroll
            for (int r = 0; r < 4; ++r)
                out[(size_t)(m + r) * 1024 + n] = acc[i][j][r] + bv;
        }
    }
}

// ---- fallback: fused kernel (full K=8192), used only if ws too small ----
#define LDK 72
__global__ __launch_bounds__(256, 2)
void taylor_gemm(const float* __restrict__ x, const float* __restrict__ trp,
                 const float* __restrict__ coef, float* __restrict__ out)
{
    __shared__ unsigned short As[BM * LDK];
    __shared__ unsigned short Bs[BN * LDK];

    const int t  = threadIdx.x;
    const int m0 = blockIdx.x * BM;
    const int n0 = blockIdx.y * BN;
    const float tr = trp[0];

    const int w    = t >> 6;
    const int lane = t & 63;
    const int wm   = (w >> 1) * 64;
    const int wn   = (w & 1) * 64;
    const int lrow = lane & 15;
    const int kq   = (lane >> 4) * 8;

    f32x4 acc[4][4];
    #pragma unroll
    for (int i = 0; i < 4; i++)
        #pragma unroll
        for (int j = 0; j < 4; j++)
            acc[i][j] = (f32x4){0.f, 0.f, 0.f, 0.f};

    const int bcol  = t & 15;
    const int brow0 = t >> 4;
    const int acol  = t & 7;
    const int arow0 = t >> 3;

    for (int k0 = 0; k0 < KFULL; k0 += 64) {
        const int i0 = k0 >> 3;
        #pragma unroll
        for (int r = 0; r < 8; ++r) {
            const int row = brow0 + r * 16;
            const float4 v = *(const float4*)(coef + (size_t)(n0 + row) * KFULL + k0 + bcol * 4);
            bf16x4 pk;
            pk[0] = (short)f2bf(v.x); pk[1] = (short)f2bf(v.y);
            pk[2] = (short)f2bf(v.z); pk[3] = (short)f2bf(v.w);
            *(bf16x4*)&Bs[row * LDK + bcol * 4] = pk;
        }
        #pragma unroll
        for (int r = 0; r < 4; ++r) {
            const int row = arow0 + r * 32;
            const float xv = x[(size_t)(m0 + row) * 1024 + i0 + acol];
            const float e  = __expf(2.0f * tr * xv);
            const float tt = 1.0f - 2.0f / (e + 1.0f);
            bf16x8 pk;
            float p = 1.0f;
            #pragma unroll
            for (int k = 0; k < 8; ++k) { pk[k] = (short)f2bf(p); p *= tt; }
            *(bf16x8*)&As[row * LDK + acol * 8] = pk;
        }
        __syncthreads();
        #pragma unroll
        for (int kk = 0; kk < 64; kk += 32) {
            bf16x8 a[4], b[4];
            #pragma unroll
            for (int i = 0; i < 4; i++)
                a[i] = *(const bf16x8*)&As[(wm + i * 16 + lrow) * LDK + kk + kq];
            #pragma unroll
            for (int j = 0; j < 4; j++)
                b[j] = *(const bf16x8*)&Bs[(wn + j * 16 + lrow) * LDK + kk + kq];
            #pragma unroll
            for (int i = 0; i < 4; i++)
                #pragma unroll
                for (int j = 0; j < 4; j++)
                    acc[i][j] = __builtin_amdgcn_mfma_f32_16x16x32_bf16(a[i], b[j], acc[i][j], 0, 0, 0);
        }
        __syncthreads();
    }

    const int crow = (lane >> 4) * 4;
    const int ccol = lane & 15;
    #pragma unroll
    for (int i = 0; i < 4; i++) {
        #pragma unroll
        for (int j = 0; j < 4; j++) {
            const int m = m0 + wm + i * 16 + crow;
            const int n = n0 + wn + j * 16 + ccol;
            #pragma unroll
            for (int r = 0; r < 4; ++r)
                out[(size_t)(m + r) * 1024 + n] = acc[i][j][r];
        }
    }
}

extern "C" void kernel_launch(void* const* d_in, const int* in_sizes, int n_in,
                              void* d_out, int out_size, void* d_ws, size_t ws_size,
                              hipStream_t stream) {
    const float* x    = (const float*)d_in[0];
    const float* trp  = (const float*)d_in[1];
    const float* coef = (const float*)d_in[2];
    float* out = (float*)d_out;

    const size_t A_BYTES    = (size_t)8192 * KT * 2;   // 117,440,512
    const size_t COEF_BYTES = (size_t)1024 * KT * 2;   //  14,680,064
    const size_t BIAS_BYTES = 1024 * sizeof(float);

    if (ws_size >= A_BYTES + COEF_BYTES + BIAS_BYTES) {
        unsigned short* A_bf    = (unsigned short*)d_ws;
        unsigned short* coef_bf = (unsigned short*)((char*)d_ws + A_BYTES);
        float*          bias    = (float*)((char*)d_ws + A_BYTES + COEF_BYTES);

        prep<<<dim3(CVT_BLOCKS + TANH_BLOCKS), dim3(256), 0, stream>>>(
            x, trp, coef, coef_bf, A_bf, bias);
        gemm_bt<<<dim3(8192 / BM, 1024 / BN), dim3(256), 0, stream>>>(
            A_bf, coef_bf, bias, out);
    } else {
        taylor_gemm<<<dim3(8192 / BM, 1024 / BN), dim3(256), 0, stream>>>(x, trp, coef, out);
    }
}

// Round 5
// 287.898 us; speedup vs baseline: 1.2991x; 1.2991x over previous
//
#include <hip/hip_runtime.h>
#include <hip/hip_bf16.h>

// out[b,j] = sum_{i,k} coef[j,i,k] * tanh(x[b,i])^k
// B=8192, IN=1024, OUT=1024, ORDER=7.
// k=0 plane -> per-j bias (computed in prep, added in gemm epilogue).
// GEMM: M=8192, N=1024, K=IN*7=7168, bf16 MFMA.
//
// Round 13: minimum 2-phase double-buffered gemm (T3 recipe):
//   - block 256x128, 8 waves (512 thr) of 64x64 each, BK=64.
//   - LDS 96 KB: As[2][256*64] + Bs[2][128*64] -> 1 block/CU, 2 waves/SIMD.
//   - per tile: {STAGE(buf^1, t+1); ds_read buf; 32 MFMA; vmcnt(0); barrier}.
//     The vmcnt(0) waits loads issued ONE FULL TILE earlier (~1500cy window
//     > ~900cy HBM latency) -> stage drain off the critical path. One barrier
//     + one vmcnt per 64-K (same barrier rate as round-11's cold-stage).
//   - grid 32x8 = 256 blocks = 1/CU; bid = x+32y -> A m-panel sharers (same
//     x, all y) land on same XCD.
//   - XOR swizzle unchanged: LDS slot s (16B chunks, 8/row) of row r holds
//     global chunk s^(r&7); linear LDS dest + pre-swizzled global source.
//   Round-12 post-mortem: B-in-VGPR gather put L2 latency on the MFMA chain
//   (MfmaUtil 18%, VALUBusy 6%) and occupancy never rose. Reverted.
//   Calibrated model (r11 counters): matrix 51%, LDS pipe 63%, drain ~35%.

#define KT 7168
#define KFULL 8192

// 2-phase gemm tile
#define TM 256
#define TN 128
#define TK 64
#define NT (KT / TK)   // 112

// fallback tile
#define BM 128
#define BN 128

typedef short bf16x8 __attribute__((ext_vector_type(8)));
typedef short bf16x4 __attribute__((ext_vector_type(4)));
typedef float f32x4  __attribute__((ext_vector_type(4)));

__device__ __forceinline__ unsigned short f2bf(float f) {
    union { __hip_bfloat16 h; unsigned short u; } v;
    v.h = __float2bfloat16(f);   // RTE
    return v.u;
}

__device__ __forceinline__ void gload_lds16(const void* gp, void* lp) {
    __builtin_amdgcn_global_load_lds(
        (const __attribute__((address_space(1))) void*)gp,
        (__attribute__((address_space(3))) void*)lp, 16, 0, 0);
}

// raw workgroup barrier with compiler memory fence (no vmcnt/lgkmcnt drain).
#define BARRIER() do { \
    asm volatile("" ::: "memory"); \
    __builtin_amdgcn_s_barrier(); \
    asm volatile("" ::: "memory"); \
} while (0)

// ---- pass 1: prep (plane-major, LDS-free) — unchanged from round 11 ----
#define CVT_BLOCKS  512
#define TANH_BLOCKS 4096

__global__ __launch_bounds__(256)
void prep(const float* __restrict__ x, const float* __restrict__ trp,
          const float* __restrict__ coef, unsigned short* __restrict__ coef_bf,
          unsigned short* __restrict__ A, float* __restrict__ bias) {
    __shared__ float redbuf[4];

    const int t   = threadIdx.x;
    const int blk = blockIdx.x;
    const int rl  = t >> 7;        // row_local 0/1
    const int ig  = t & 127;       // i-group (8 i's each)

    if (blk < CVT_BLOCKS) {
        // ---- coef conversion: row j, k=1..7 -> planes 0..6; k=0 -> bias ----
        const int j = blk * 2 + rl;
        const float* src = coef + (size_t)j * KFULL + ig * 64;
        float k0sum = 0.f;
        bf16x8 pl[7];
        #pragma unroll
        for (int i = 0; i < 8; ++i) {
            const float4 f0 = *(const float4*)(src + i * 8);
            const float4 f1 = *(const float4*)(src + i * 8 + 4);
            k0sum += f0.x;
            pl[0][i] = (short)f2bf(f0.y); pl[1][i] = (short)f2bf(f0.z);
            pl[2][i] = (short)f2bf(f0.w); pl[3][i] = (short)f2bf(f1.x);
            pl[4][i] = (short)f2bf(f1.y); pl[5][i] = (short)f2bf(f1.z);
            pl[6][i] = (short)f2bf(f1.w);
        }
        #pragma unroll
        for (int off = 32; off > 0; off >>= 1) k0sum += __shfl_down(k0sum, off, 64);
        if ((t & 63) == 0) redbuf[t >> 6] = k0sum;
        __syncthreads();
        if (t == 0)   bias[j] = redbuf[0] + redbuf[1];
        if (t == 128) bias[j] = redbuf[2] + redbuf[3];

        unsigned short* dst = coef_bf + (size_t)j * KT + ig * 8;
        #pragma unroll
        for (int p = 0; p < 7; ++p)
            *(bf16x8*)(dst + p * 1024) = pl[p];   // coalesced: 16B/lane contiguous
    } else {
        // ---- tanh powers: row bb, plane p holds tanh(x)^(p+1) ----
        const int bb = (blk - CVT_BLOCKS) * 2 + rl;
        const float tr = trp[0];
        const float* xp = x + (size_t)bb * 1024 + ig * 8;
        const float4 x0 = *(const float4*)xp;
        const float4 x1 = *(const float4*)(xp + 4);
        const float xs[8] = {x0.x, x0.y, x0.z, x0.w, x1.x, x1.y, x1.z, x1.w};
        bf16x8 pl[7];
        #pragma unroll
        for (int i = 0; i < 8; ++i) {
            const float e  = __expf(2.0f * tr * xs[i]);
            const float tt = 1.0f - 2.0f * __builtin_amdgcn_rcpf(e + 1.0f);  // tanh(tr*x)
            float pw = tt;
            #pragma unroll
            for (int p = 0; p < 7; ++p) { pl[p][i] = (short)f2bf(pw); pw *= tt; }
        }
        unsigned short* dst = A + (size_t)bb * KT + ig * 8;
        #pragma unroll
        for (int p = 0; p < 7; ++p)
            *(bf16x8*)(dst + p * 1024) = pl[p];   // coalesced: 16B/lane contiguous
    }
}

// ---- pass 2: NT GEMM (K=7168), 2-phase double-buffered ----
__global__ __launch_bounds__(512, 2)
void gemm_bt(const unsigned short* __restrict__ A, const unsigned short* __restrict__ Bt,
             const float* __restrict__ bias, float* __restrict__ out)
{
    __shared__ unsigned short As[2][TM * TK];   // 2 x 32 KB
    __shared__ unsigned short Bs[2][TN * TK];   // 2 x 16 KB  -> 96 KB, 1 block/CU

    const int t    = threadIdx.x;
    const int m0   = blockIdx.x * TM;   // x = m-tile: A-sharers land on same XCD
    const int n0   = blockIdx.y * TN;
    const int w    = t >> 6;            // 0..7
    const int lane = t & 63;
    const int wm   = (w >> 1) * 64;     // 0..192
    const int wn   = (w & 1) * 64;      // 0/64
    const int lrow = lane & 15;
    const int lq   = lane >> 4;

    // fragment-read swizzle: chunk c = kk/8 + lq lives at slot c^(row&7);
    // row&7 == lane&7 for all fragment rows (wm, wn, i*16 multiples of 8+... 16).
    const int S = ((lq ^ (lane & 7)) << 3);   // ushort offset of kk=0 slot

    // staging: thread t -> row srow (+r*64 per sweep), slot t&7 holds global
    // chunk (t&7)^(srow&7).  gload dest = wave-uniform base + lane*16B.
    const int srow = t >> 3;                  // 0..63
    const int schk = (t & 7) ^ (srow & 7);
    const size_t aG = (size_t)(m0 + srow) * KT + schk * 8;
    const size_t bG = (size_t)(n0 + srow) * KT + schk * 8;
    const int wofs = w * 512;                 // ushorts

    f32x4 acc[4][4];
    #pragma unroll
    for (int i = 0; i < 4; i++)
        #pragma unroll
        for (int j = 0; j < 4; j++)
            acc[i][j] = (f32x4){0.f, 0.f, 0.f, 0.f};

    // prologue: stage tile 0 -> buf 0, drain, barrier
    #pragma unroll
    for (int r = 0; r < 4; ++r)
        gload_lds16(A + aG + (size_t)(r * 64) * KT, &As[0][r * 4096 + wofs]);
    #pragma unroll
    for (int r = 0; r < 2; ++r)
        gload_lds16(Bt + bG + (size_t)(r * 64) * KT, &Bs[0][r * 4096 + wofs]);
    asm volatile("s_waitcnt vmcnt(0)" ::: "memory");
    BARRIER();

    for (int kt = 0; kt < NT; ++kt) {
        const int cur = kt & 1;

        // STAGE tile kt+1 into the other buffer: loads fly under this tile's
        // ds_read + MFMA window (~1500cy), waited only at the tile-end vmcnt.
        if (kt + 1 < NT) {
            const size_t ko = (size_t)(kt + 1) * TK;
            #pragma unroll
            for (int r = 0; r < 4; ++r)
                gload_lds16(A + aG + (size_t)(r * 64) * KT + ko, &As[cur ^ 1][r * 4096 + wofs]);
            #pragma unroll
            for (int r = 0; r < 2; ++r)
                gload_lds16(Bt + bG + (size_t)(r * 64) * KT + ko, &Bs[cur ^ 1][r * 4096 + wofs]);
        }

        const unsigned short* as = As[cur];
        const unsigned short* bs = Bs[cur];
        bf16x8 a[2][4], b[2][4];
        #pragma unroll
        for (int i = 0; i < 4; ++i) {
            const int ro = (wm + i * 16 + lrow) * TK + S;
            a[0][i] = *(const bf16x8*)&as[ro];
            a[1][i] = *(const bf16x8*)&as[ro ^ 32];   // kk=32: slot^4
        }
        #pragma unroll
        for (int j = 0; j < 4; ++j) {
            const int ro = (wn + j * 16 + lrow) * TK + S;
            b[0][j] = *(const bf16x8*)&bs[ro];
            b[1][j] = *(const bf16x8*)&bs[ro ^ 32];
        }
        #pragma unroll
        for (int kk = 0; kk < 2; ++kk)
            #pragma unroll
            for (int i = 0; i < 4; ++i)
                #pragma unroll
                for (int j = 0; j < 4; ++j)
                    acc[i][j] = __builtin_amdgcn_mfma_f32_16x16x32_bf16(
                        a[kk][i], b[kk][j], acc[i][j], 0, 0, 0);

        // next tile's loads (issued at top) have had the full window; wait
        // them, then barrier so every wave's LDS writes are visible.
        asm volatile("s_waitcnt vmcnt(0)" ::: "memory");
        BARRIER();
    }

    const int crow = (lane >> 4) * 4;
    const int ccol = lane & 15;
    #pragma unroll
    for (int j = 0; j < 4; j++) {
        const int n = n0 + wn + j * 16 + ccol;
        const float bv = bias[n];
        #pragma unroll
        for (int i = 0; i < 4; i++) {
            const int m = m0 + wm + i * 16 + crow;
            #pragma unroll
            for (int r = 0; r < 4; ++r)
                out[(size_t)(m + r) * 1024 + n] = acc[i][j][r] + bv;
        }
    }
}

// ---- fallback: fused kernel (full K=8192), used only if ws too small ----
#define LDK 72
__global__ __launch_bounds__(256, 2)
void taylor_gemm(const float* __restrict__ x, const float* __restrict__ trp,
                 const float* __restrict__ coef, float* __restrict__ out)
{
    __shared__ unsigned short Afs[BM * LDK];
    __shared__ unsigned short Bfs[BN * LDK];

    const int t  = threadIdx.x;
    const int m0 = blockIdx.x * BM;
    const int n0 = blockIdx.y * BN;
    const float tr = trp[0];

    const int w    = t >> 6;
    const int lane = t & 63;
    const int wm   = (w >> 1) * 64;
    const int wn   = (w & 1) * 64;
    const int lrow = lane & 15;
    const int kq   = (lane >> 4) * 8;

    f32x4 acc[4][4];
    #pragma unroll
    for (int i = 0; i < 4; i++)
        #pragma unroll
        for (int j = 0; j < 4; j++)
            acc[i][j] = (f32x4){0.f, 0.f, 0.f, 0.f};

    const int bcol  = t & 15;
    const int brow0 = t >> 4;
    const int acol  = t & 7;
    const int arow0 = t >> 3;

    for (int k0 = 0; k0 < KFULL; k0 += 64) {
        const int i0 = k0 >> 3;
        #pragma unroll
        for (int r = 0; r < 8; ++r) {
            const int row = brow0 + r * 16;
            const float4 v = *(const float4*)(coef + (size_t)(n0 + row) * KFULL + k0 + bcol * 4);
            bf16x4 pk;
            pk[0] = (short)f2bf(v.x); pk[1] = (short)f2bf(v.y);
            pk[2] = (short)f2bf(v.z); pk[3] = (short)f2bf(v.w);
            *(bf16x4*)&Bfs[row * LDK + bcol * 4] = pk;
        }
        #pragma unroll
        for (int r = 0; r < 4; ++r) {
            const int row = arow0 + r * 32;
            const float xv = x[(size_t)(m0 + row) * 1024 + i0 + acol];
            const float e  = __expf(2.0f * tr * xv);
            const float tt = 1.0f - 2.0f / (e + 1.0f);
            bf16x8 pk;
            float p = 1.0f;
            #pragma unroll
            for (int k = 0; k < 8; ++k) { pk[k] = (short)f2bf(p); p *= tt; }
            *(bf16x8*)&Afs[row * LDK + acol * 8] = pk;
        }
        __syncthreads();
        #pragma unroll
        for (int kk = 0; kk < 64; kk += 32) {
            bf16x8 a[4], b[4];
            #pragma unroll
            for (int i = 0; i < 4; i++)
                a[i] = *(const bf16x8*)&Afs[(wm + i * 16 + lrow) * LDK + kk + kq];
            #pragma unroll
            for (int j = 0; j < 4; j++)
                b[j] = *(const bf16x8*)&Bfs[(wn + j * 16 + lrow) * LDK + kk + kq];
            #pragma unroll
            for (int i = 0; i < 4; i++)
                #pragma unroll
                for (int j = 0; j < 4; j++)
                    acc[i][j] = __builtin_amdgcn_mfma_f32_16x16x32_bf16(a[i], b[j], acc[i][j], 0, 0, 0);
        }
        __syncthreads();
    }

    const int crow = (lane >> 4) * 4;
    const int ccol = lane & 15;
    #pragma unroll
    for (int i = 0; i < 4; i++) {
        #pragma unroll
        for (int j = 0; j < 4; j++) {
            const int m = m0 + wm + i * 16 + crow;
            const int n = n0 + wn + j * 16 + ccol;
            #pragma unroll
            for (int r = 0; r < 4; ++r)
                out[(size_t)(m + r) * 1024 + n] = acc[i][j][r];
        }
    }
}

extern "C" void kernel_launch(void* const* d_in, const int* in_sizes, int n_in,
                              void* d_out, int out_size, void* d_ws, size_t ws_size,
                              hipStream_t stream) {
    const float* x    = (const float*)d_in[0];
    const float* trp  = (const float*)d_in[1];
    const float* coef = (const float*)d_in[2];
    float* out = (float*)d_out;

    const size_t A_BYTES    = (size_t)8192 * KT * 2;   // 117,440,512
    const size_t COEF_BYTES = (size_t)1024 * KT * 2;   //  14,680,064
    const size_t BIAS_BYTES = 1024 * sizeof(float);

    if (ws_size >= A_BYTES + COEF_BYTES + BIAS_BYTES) {
        unsigned short* A_bf    = (unsigned short*)d_ws;
        unsigned short* coef_bf = (unsigned short*)((char*)d_ws + A_BYTES);
        float*          bias    = (float*)((char*)d_ws + A_BYTES + COEF_BYTES);

        prep<<<dim3(CVT_BLOCKS + TANH_BLOCKS), dim3(256), 0, stream>>>(
            x, trp, coef, coef_bf, A_bf, bias);
        gemm_bt<<<dim3(8192 / TM, 1024 / TN), dim3(512), 0, stream>>>(
            A_bf, coef_bf, bias, out);
    } else {
        taylor_gemm<<<dim3(8192 / BM, 1024 / BN), dim3(256), 0, stream>>>(x, trp, coef, out);
    }
}

// Round 6
// 238.277 us; speedup vs baseline: 1.5697x; 1.2083x over previous
//
#include <hip/hip_runtime.h>
#include <hip/hip_bf16.h>

// out[b,j] = sum_{i,k} coef[j,i,k] * tanh(x[b,i])^k
// B=8192, IN=1024, OUT=1024, ORDER=7.
// k=0 plane -> per-j bias (computed in prep, added in gemm epilogue).
// GEMM: M=8192, N=1024, K=IN*7=7168, bf16 MFMA.
//
// Round 14: r11 memory structure VERBATIM (BK=128 cold-stage, 64KB LDS,
// 2 anti-phased blocks/CU, 1 barrier-pair per 128-K — measured 114us/47%).
// Pipelining post-mortem (r9=135, r10=133, r13=176 vs r11=114): intra-block
// software pipelines lose to inter-block anti-phasing here. Reverted for good.
// This round's single change: 16x16x32 -> 32x32x16 MFMA (same FLOPs, HALF the
// MFMA instructions, same 32 ds_read_b128/wave/tile). r11 counters imply
// ~9cy effective pipe occupancy per MFMA -> instruction-issue-limited; 32x32
// is 4096 vs 3378 FLOP/cy. C/D layout: col=lane&31,
// row=(reg&3)+8*(reg>>2)+4*(lane>>5) (m74/m101-verified).

#define KT 7168
#define KFULL 8192

// gemm tile (r11)
#define BM 128
#define BN 128
#define BK 128

typedef short bf16x8 __attribute__((ext_vector_type(8)));
typedef short bf16x4 __attribute__((ext_vector_type(4)));
typedef float f32x4  __attribute__((ext_vector_type(4)));
typedef float f32x16 __attribute__((ext_vector_type(16)));

__device__ __forceinline__ unsigned short f2bf(float f) {
    union { __hip_bfloat16 h; unsigned short u; } v;
    v.h = __float2bfloat16(f);   // RTE
    return v.u;
}

__device__ __forceinline__ void gload_lds16(const void* gp, void* lp) {
    __builtin_amdgcn_global_load_lds(
        (const __attribute__((address_space(1))) void*)gp,
        (__attribute__((address_space(3))) void*)lp, 16, 0, 0);
}

// ---- pass 1: prep (plane-major, LDS-free) — unchanged (BW floor) ----
#define CVT_BLOCKS  512
#define TANH_BLOCKS 4096

__global__ __launch_bounds__(256)
void prep(const float* __restrict__ x, const float* __restrict__ trp,
          const float* __restrict__ coef, unsigned short* __restrict__ coef_bf,
          unsigned short* __restrict__ A, float* __restrict__ bias) {
    __shared__ float redbuf[4];

    const int t   = threadIdx.x;
    const int blk = blockIdx.x;
    const int rl  = t >> 7;        // row_local 0/1
    const int ig  = t & 127;       // i-group (8 i's each)

    if (blk < CVT_BLOCKS) {
        // ---- coef conversion: row j, k=1..7 -> planes 0..6; k=0 -> bias ----
        const int j = blk * 2 + rl;
        const float* src = coef + (size_t)j * KFULL + ig * 64;
        float k0sum = 0.f;
        bf16x8 pl[7];
        #pragma unroll
        for (int i = 0; i < 8; ++i) {
            const float4 f0 = *(const float4*)(src + i * 8);
            const float4 f1 = *(const float4*)(src + i * 8 + 4);
            k0sum += f0.x;
            pl[0][i] = (short)f2bf(f0.y); pl[1][i] = (short)f2bf(f0.z);
            pl[2][i] = (short)f2bf(f0.w); pl[3][i] = (short)f2bf(f1.x);
            pl[4][i] = (short)f2bf(f1.y); pl[5][i] = (short)f2bf(f1.z);
            pl[6][i] = (short)f2bf(f1.w);
        }
        #pragma unroll
        for (int off = 32; off > 0; off >>= 1) k0sum += __shfl_down(k0sum, off, 64);
        if ((t & 63) == 0) redbuf[t >> 6] = k0sum;
        __syncthreads();
        if (t == 0)   bias[j] = redbuf[0] + redbuf[1];
        if (t == 128) bias[j] = redbuf[2] + redbuf[3];

        unsigned short* dst = coef_bf + (size_t)j * KT + ig * 8;
        #pragma unroll
        for (int p = 0; p < 7; ++p)
            *(bf16x8*)(dst + p * 1024) = pl[p];   // coalesced: 16B/lane contiguous
    } else {
        // ---- tanh powers: row bb, plane p holds tanh(x)^(p+1) ----
        const int bb = (blk - CVT_BLOCKS) * 2 + rl;
        const float tr = trp[0];
        const float* xp = x + (size_t)bb * 1024 + ig * 8;
        const float4 x0 = *(const float4*)xp;
        const float4 x1 = *(const float4*)(xp + 4);
        const float xs[8] = {x0.x, x0.y, x0.z, x0.w, x1.x, x1.y, x1.z, x1.w};
        bf16x8 pl[7];
        #pragma unroll
        for (int i = 0; i < 8; ++i) {
            const float e  = __expf(2.0f * tr * xs[i]);
            const float tt = 1.0f - 2.0f * __builtin_amdgcn_rcpf(e + 1.0f);  // tanh(tr*x)
            float pw = tt;
            #pragma unroll
            for (int p = 0; p < 7; ++p) { pl[p][i] = (short)f2bf(pw); pw *= tt; }
        }
        unsigned short* dst = A + (size_t)bb * KT + ig * 8;
        #pragma unroll
        for (int p = 0; p < 7; ++p)
            *(bf16x8*)(dst + p * 1024) = pl[p];   // coalesced: 16B/lane contiguous
    }
}

// ---- pass 2: NT GEMM (K=7168), r11 staging + 32x32x16 MFMA ----
// XOR swizzle (16 chunks/row): slot s of row m holds global chunk s^(m&15).
__global__ __launch_bounds__(256, 2)
void gemm_bt(const unsigned short* __restrict__ A, const unsigned short* __restrict__ Bt,
             const float* __restrict__ bias, float* __restrict__ out)
{
    __shared__ unsigned short As[BM * BK];   // 32 KB
    __shared__ unsigned short Bs[BN * BK];   // 32 KB

    const int t    = threadIdx.x;
    const int m0   = blockIdx.x * BM;   // x = m-tile: A-sharers land on same XCD
    const int n0   = blockIdx.y * BN;
    const int w    = t >> 6;
    const int lane = t & 63;
    const int wm   = (w >> 1) * 64;
    const int wn   = (w & 1) * 64;
    const int l31  = lane & 31;         // fragment row (32-row frags)
    const int hi   = lane >> 5;         // k-half within frag (8 elems each)

    // staging (identical to r11): thread t covers row srow + r*16 (r=0..7);
    // fetches swizzled chunk schunk = (t&15)^srow so LDS slot s of row m
    // holds chunk s^(m&15).
    const int srow   = t >> 4;           // 0..15
    const int schunk = (t & 15) ^ srow;
    const int wbase  = w * 512;          // ushort units; +lane*16B applied by HW

    // fragment-read swizzle: frag (row, kstep ks) needs global chunk
    // c = ks*2 + hi at slot c^(row&15), row&15 == lane&15.
    // ushort offset within row = slot*8 = (ks*16) ^ ((hi^(lane&15))*8).
    const int sx = ((hi ^ (lane & 15)) << 3);

    f32x16 acc[2][2];
    #pragma unroll
    for (int i = 0; i < 2; i++)
        #pragma unroll
        for (int j = 0; j < 2; j++)
            #pragma unroll
            for (int e = 0; e < 16; e++)
                acc[i][j][e] = 0.f;

    const size_t abase = (size_t)(m0 + srow) * KT + schunk * 8;
    const size_t bbase = (size_t)(n0 + srow) * KT + schunk * 8;

    for (int k0 = 0; k0 < KT; k0 += BK) {
        #pragma unroll
        for (int r = 0; r < 8; ++r)
            gload_lds16(A + abase + (size_t)r * 16 * KT + k0, &As[r * 2048 + wbase]);
        #pragma unroll
        for (int r = 0; r < 8; ++r)
            gload_lds16(Bt + bbase + (size_t)r * 16 * KT + k0, &Bs[r * 2048 + wbase]);

        __syncthreads();

        #pragma unroll
        for (int ks = 0; ks < 8; ++ks) {           // K=16 per step
            const int koff = (ks << 4) ^ sx;       // swizzled ushort offset
            bf16x8 a[2], b[2];
            #pragma unroll
            for (int i = 0; i < 2; i++)
                a[i] = *(const bf16x8*)&As[(wm + i * 32 + l31) * BK + koff];
            #pragma unroll
            for (int j = 0; j < 2; j++)
                b[j] = *(const bf16x8*)&Bs[(wn + j * 32 + l31) * BK + koff];
            #pragma unroll
            for (int i = 0; i < 2; i++)
                #pragma unroll
                for (int j = 0; j < 2; j++)
                    acc[i][j] = __builtin_amdgcn_mfma_f32_32x32x16_bf16(
                        a[i], b[j], acc[i][j], 0, 0, 0);
        }

        __syncthreads();
    }

    // epilogue: C/D layout col=lane&31, row=(reg&3)+8*(reg>>2)+4*(lane>>5)
    #pragma unroll
    for (int j = 0; j < 2; j++) {
        const int n = n0 + wn + j * 32 + l31;
        const float bv = bias[n];
        #pragma unroll
        for (int i = 0; i < 2; i++) {
            const int mb = m0 + wm + i * 32 + 4 * hi;
            #pragma unroll
            for (int r = 0; r < 16; ++r) {
                const int m = mb + (r & 3) + 8 * (r >> 2);
                out[(size_t)m * 1024 + n] = acc[i][j][r] + bv;
            }
        }
    }
}

// ---- fallback: fused kernel (full K=8192), used only if ws too small ----
#define LDK 72
__global__ __launch_bounds__(256, 2)
void taylor_gemm(const float* __restrict__ x, const float* __restrict__ trp,
                 const float* __restrict__ coef, float* __restrict__ out)
{
    __shared__ unsigned short Afs[BM * LDK];
    __shared__ unsigned short Bfs[BN * LDK];

    const int t  = threadIdx.x;
    const int m0 = blockIdx.x * BM;
    const int n0 = blockIdx.y * BN;
    const float tr = trp[0];

    const int w    = t >> 6;
    const int lane = t & 63;
    const int wm   = (w >> 1) * 64;
    const int wn   = (w & 1) * 64;
    const int lrow = lane & 15;
    const int kq   = (lane >> 4) * 8;

    f32x4 acc[4][4];
    #pragma unroll
    for (int i = 0; i < 4; i++)
        #pragma unroll
        for (int j = 0; j < 4; j++)
            acc[i][j] = (f32x4){0.f, 0.f, 0.f, 0.f};

    const int bcol  = t & 15;
    const int brow0 = t >> 4;
    const int acol  = t & 7;
    const int arow0 = t >> 3;

    for (int k0 = 0; k0 < KFULL; k0 += 64) {
        const int i0 = k0 >> 3;
        #pragma unroll
        for (int r = 0; r < 8; ++r) {
            const int row = brow0 + r * 16;
            const float4 v = *(const float4*)(coef + (size_t)(n0 + row) * KFULL + k0 + bcol * 4);
            bf16x4 pk;
            pk[0] = (short)f2bf(v.x); pk[1] = (short)f2bf(v.y);
            pk[2] = (short)f2bf(v.z); pk[3] = (short)f2bf(v.w);
            *(bf16x4*)&Bfs[row * LDK + bcol * 4] = pk;
        }
        #pragma unroll
        for (int r = 0; r < 4; ++r) {
            const int row = arow0 + r * 32;
            const float xv = x[(size_t)(m0 + row) * 1024 + i0 + acol];
            const float e  = __expf(2.0f * tr * xv);
            const float tt = 1.0f - 2.0f / (e + 1.0f);
            bf16x8 pk;
            float p = 1.0f;
            #pragma unroll
            for (int k = 0; k < 8; ++k) { pk[k] = (short)f2bf(p); p *= tt; }
            *(bf16x8*)&Afs[row * LDK + acol * 8] = pk;
        }
        __syncthreads();
        #pragma unroll
        for (int kk = 0; kk < 64; kk += 32) {
            bf16x8 a[4], b[4];
            #pragma unroll
            for (int i = 0; i < 4; i++)
                a[i] = *(const bf16x8*)&Afs[(wm + i * 16 + lrow) * LDK + kk + kq];
            #pragma unroll
            for (int j = 0; j < 4; j++)
                b[j] = *(const bf16x8*)&Bfs[(wn + j * 16 + lrow) * LDK + kk + kq];
            #pragma unroll
            for (int i = 0; i < 4; i++)
                #pragma unroll
                for (int j = 0; j < 4; j++)
                    acc[i][j] = __builtin_amdgcn_mfma_f32_16x16x32_bf16(a[i], b[j], acc[i][j], 0, 0, 0);
        }
        __syncthreads();
    }

    const int crow = (lane >> 4) * 4;
    const int ccol = lane & 15;
    #pragma unroll
    for (int i = 0; i < 4; i++) {
        #pragma unroll
        for (int j = 0; j < 4; j++) {
            const int m = m0 + wm + i * 16 + crow;
            const int n = n0 + wn + j * 16 + ccol;
            #pragma unroll
            for (int r = 0; r < 4; ++r)
                out[(size_t)(m + r) * 1024 + n] = acc[i][j][r];
        }
    }
}

extern "C" void kernel_launch(void* const* d_in, const int* in_sizes, int n_in,
                              void* d_out, int out_size, void* d_ws, size_t ws_size,
                              hipStream_t stream) {
    const float* x    = (const float*)d_in[0];
    const float* trp  = (const float*)d_in[1];
    const float* coef = (const float*)d_in[2];
    float* out = (float*)d_out;

    const size_t A_BYTES    = (size_t)8192 * KT * 2;   // 117,440,512
    const size_t COEF_BYTES = (size_t)1024 * KT * 2;   //  14,680,064
    const size_t BIAS_BYTES = 1024 * sizeof(float);

    if (ws_size >= A_BYTES + COEF_BYTES + BIAS_BYTES) {
        unsigned short* A_bf    = (unsigned short*)d_ws;
        unsigned short* coef_bf = (unsigned short*)((char*)d_ws + A_BYTES);
        float*          bias    = (float*)((char*)d_ws + A_BYTES + COEF_BYTES);

        prep<<<dim3(CVT_BLOCKS + TANH_BLOCKS), dim3(256), 0, stream>>>(
            x, trp, coef, coef_bf, A_bf, bias);
        gemm_bt<<<dim3(8192 / BM, 1024 / BN), dim3(256), 0, stream>>>(
            A_bf, coef_bf, bias, out);
    } else {
        taylor_gemm<<<dim3(8192 / BM, 1024 / BN), dim3(256), 0, stream>>>(x, trp, coef, out);
    }
}

// Round 7
// 230.179 us; speedup vs baseline: 1.6249x; 1.0352x over previous
//
#include <hip/hip_runtime.h>
#include <hip/hip_bf16.h>

// out[b,j] = sum_{i,k} coef[j,i,k] * tanh(x[b,i])^k
// B=8192, IN=1024, OUT=1024, ORDER=7.
// k=0 plane -> per-j bias (computed in prep, added in gemm epilogue).
// GEMM: M=8192, N=1024, K=IN*7=7168, bf16 MFMA.
//
// Round 15: r11 kernel (114us, MfmaUtil 47%) + ONE change: anti-phase stagger.
// Cycle accounting of r11 (per CU, per BK=128 round): MFMA 2483cy + staging
// 2290cy (L2-bound) with ~zero overlap (sum = 4773 ~= 4900 measured). The two
// co-resident blocks are IN-PHASE (dispatched together, L2 contention is a
// stable synchronizer): both stage together, both compute together. Blocks id
// and id+256 share a CU (round-robin dispatch, 512 blocks / 256 CUs); giving
// the second set a one-time s_sleep(19) (~1216cy ~ half a round) before the
// K-loop flips the pair to ANTI-phase: stager gets full L2 while partner
// runs MFMA -- also a fixed point, round -> ~2500cy for two tiles.
// Numerically a no-op (sleep only delays). 32x32 MFMA (r14) reverted:
// 130us, latency-bound at 4 acc chains.

#define KT 7168
#define KFULL 8192

// gemm tile (r11)
#define BM 128
#define BN 128
#define BK 128

typedef short bf16x8 __attribute__((ext_vector_type(8)));
typedef short bf16x4 __attribute__((ext_vector_type(4)));
typedef float f32x4  __attribute__((ext_vector_type(4)));

__device__ __forceinline__ unsigned short f2bf(float f) {
    union { __hip_bfloat16 h; unsigned short u; } v;
    v.h = __float2bfloat16(f);   // RTE
    return v.u;
}

__device__ __forceinline__ void gload_lds16(const void* gp, void* lp) {
    __builtin_amdgcn_global_load_lds(
        (const __attribute__((address_space(1))) void*)gp,
        (__attribute__((address_space(3))) void*)lp, 16, 0, 0);
}

// ---- pass 1: prep (plane-major, LDS-free) — unchanged (BW floor) ----
#define CVT_BLOCKS  512
#define TANH_BLOCKS 4096

__global__ __launch_bounds__(256)
void prep(const float* __restrict__ x, const float* __restrict__ trp,
          const float* __restrict__ coef, unsigned short* __restrict__ coef_bf,
          unsigned short* __restrict__ A, float* __restrict__ bias) {
    __shared__ float redbuf[4];

    const int t   = threadIdx.x;
    const int blk = blockIdx.x;
    const int rl  = t >> 7;        // row_local 0/1
    const int ig  = t & 127;       // i-group (8 i's each)

    if (blk < CVT_BLOCKS) {
        // ---- coef conversion: row j, k=1..7 -> planes 0..6; k=0 -> bias ----
        const int j = blk * 2 + rl;
        const float* src = coef + (size_t)j * KFULL + ig * 64;
        float k0sum = 0.f;
        bf16x8 pl[7];
        #pragma unroll
        for (int i = 0; i < 8; ++i) {
            const float4 f0 = *(const float4*)(src + i * 8);
            const float4 f1 = *(const float4*)(src + i * 8 + 4);
            k0sum += f0.x;
            pl[0][i] = (short)f2bf(f0.y); pl[1][i] = (short)f2bf(f0.z);
            pl[2][i] = (short)f2bf(f0.w); pl[3][i] = (short)f2bf(f1.x);
            pl[4][i] = (short)f2bf(f1.y); pl[5][i] = (short)f2bf(f1.z);
            pl[6][i] = (short)f2bf(f1.w);
        }
        #pragma unroll
        for (int off = 32; off > 0; off >>= 1) k0sum += __shfl_down(k0sum, off, 64);
        if ((t & 63) == 0) redbuf[t >> 6] = k0sum;
        __syncthreads();
        if (t == 0)   bias[j] = redbuf[0] + redbuf[1];
        if (t == 128) bias[j] = redbuf[2] + redbuf[3];

        unsigned short* dst = coef_bf + (size_t)j * KT + ig * 8;
        #pragma unroll
        for (int p = 0; p < 7; ++p)
            *(bf16x8*)(dst + p * 1024) = pl[p];   // coalesced: 16B/lane contiguous
    } else {
        // ---- tanh powers: row bb, plane p holds tanh(x)^(p+1) ----
        const int bb = (blk - CVT_BLOCKS) * 2 + rl;
        const float tr = trp[0];
        const float* xp = x + (size_t)bb * 1024 + ig * 8;
        const float4 x0 = *(const float4*)xp;
        const float4 x1 = *(const float4*)(xp + 4);
        const float xs[8] = {x0.x, x0.y, x0.z, x0.w, x1.x, x1.y, x1.z, x1.w};
        bf16x8 pl[7];
        #pragma unroll
        for (int i = 0; i < 8; ++i) {
            const float e  = __expf(2.0f * tr * xs[i]);
            const float tt = 1.0f - 2.0f * __builtin_amdgcn_rcpf(e + 1.0f);  // tanh(tr*x)
            float pw = tt;
            #pragma unroll
            for (int p = 0; p < 7; ++p) { pl[p][i] = (short)f2bf(pw); pw *= tt; }
        }
        unsigned short* dst = A + (size_t)bb * KT + ig * 8;
        #pragma unroll
        for (int p = 0; p < 7; ++p)
            *(bf16x8*)(dst + p * 1024) = pl[p];   // coalesced: 16B/lane contiguous
    }
}

// ---- pass 2: NT GEMM (K=7168), r11 structure + anti-phase stagger ----
// XOR swizzle (16 chunks/row): slot s of row m holds global chunk s^(m&15).
__global__ __launch_bounds__(256, 2)
void gemm_bt(const unsigned short* __restrict__ A, const unsigned short* __restrict__ Bt,
             const float* __restrict__ bias, float* __restrict__ out)
{
    __shared__ unsigned short As[BM * BK];   // 32 KB
    __shared__ unsigned short Bs[BN * BK];   // 32 KB

    const int t    = threadIdx.x;
    const int m0   = blockIdx.x * BM;   // x = m-tile: A-sharers land on same XCD
    const int n0   = blockIdx.y * BN;
    const int w    = t >> 6;
    const int lane = t & 63;
    const int wm   = (w >> 1) * 64;
    const int wn   = (w & 1) * 64;
    const int lrow = lane & 15;

    // anti-phase stagger: blocks id and id+256 co-reside on a CU (512 blocks,
    // round-robin over 256 CUs). Delay the second set by ~half a round so the
    // pair interleaves stage<->compute instead of phase-locking on L2.
    const int bid = blockIdx.x + (int)blockIdx.y * 64;
    if (bid & 256) __builtin_amdgcn_s_sleep(19);   // ~1216 cy, one-time

    // staging: thread t covers row srow + r*16 (r=0..7); fetches swizzled
    // chunk schunk = (t&15)^srow so LDS slot s of row m holds chunk s^(m&15).
    const int srow   = t >> 4;           // 0..15
    const int schunk = (t & 15) ^ srow;
    const int wbase  = w * 512;          // ushort units; +lane*16B applied by HW

    f32x4 acc[4][4];
    #pragma unroll
    for (int i = 0; i < 4; i++)
        #pragma unroll
        for (int j = 0; j < 4; j++)
            acc[i][j] = (f32x4){0.f, 0.f, 0.f, 0.f};

    const size_t abase = (size_t)(m0 + srow) * KT + schunk * 8;
    const size_t bbase = (size_t)(n0 + srow) * KT + schunk * 8;

    for (int k0 = 0; k0 < KT; k0 += BK) {
        #pragma unroll
        for (int r = 0; r < 8; ++r)
            gload_lds16(A + abase + (size_t)r * 16 * KT + k0, &As[r * 2048 + wbase]);
        #pragma unroll
        for (int r = 0; r < 8; ++r)
            gload_lds16(Bt + bbase + (size_t)r * 16 * KT + k0, &Bs[r * 2048 + wbase]);

        __syncthreads();

        #pragma unroll
        for (int kk = 0; kk < BK; kk += 32) {
            // global chunk c = kk/8 + quad; stored at slot c^(m&15), m&15 == lane&15
            const int soff = ((((kk >> 3) + (lane >> 4)) ^ (lane & 15)) * 8);
            bf16x8 a[4], b[4];
            #pragma unroll
            for (int i = 0; i < 4; i++)
                a[i] = *(const bf16x8*)&As[(wm + i * 16 + lrow) * BK + soff];
            #pragma unroll
            for (int j = 0; j < 4; j++)
                b[j] = *(const bf16x8*)&Bs[(wn + j * 16 + lrow) * BK + soff];
            #pragma unroll
            for (int i = 0; i < 4; i++)
                #pragma unroll
                for (int j = 0; j < 4; j++)
                    acc[i][j] = __builtin_amdgcn_mfma_f32_16x16x32_bf16(a[i], b[j], acc[i][j], 0, 0, 0);
        }

        __syncthreads();
    }

    const int crow = (lane >> 4) * 4;
    const int ccol = lane & 15;
    #pragma unroll
    for (int j = 0; j < 4; j++) {
        const int n = n0 + wn + j * 16 + ccol;
        const float bv = bias[n];
        #pragma unroll
        for (int i = 0; i < 4; i++) {
            const int m = m0 + wm + i * 16 + crow;
            #pragma unroll
            for (int r = 0; r < 4; ++r)
                out[(size_t)(m + r) * 1024 + n] = acc[i][j][r] + bv;
        }
    }
}

// ---- fallback: fused kernel (full K=8192), used only if ws too small ----
#define LDK 72
__global__ __launch_bounds__(256, 2)
void taylor_gemm(const float* __restrict__ x, const float* __restrict__ trp,
                 const float* __restrict__ coef, float* __restrict__ out)
{
    __shared__ unsigned short Afs[BM * LDK];
    __shared__ unsigned short Bfs[BN * LDK];

    const int t  = threadIdx.x;
    const int m0 = blockIdx.x * BM;
    const int n0 = blockIdx.y * BN;
    const float tr = trp[0];

    const int w    = t >> 6;
    const int lane = t & 63;
    const int wm   = (w >> 1) * 64;
    const int wn   = (w & 1) * 64;
    const int lrow = lane & 15;
    const int kq   = (lane >> 4) * 8;

    f32x4 acc[4][4];
    #pragma unroll
    for (int i = 0; i < 4; i++)
        #pragma unroll
        for (int j = 0; j < 4; j++)
            acc[i][j] = (f32x4){0.f, 0.f, 0.f, 0.f};

    const int bcol  = t & 15;
    const int brow0 = t >> 4;
    const int acol  = t & 7;
    const int arow0 = t >> 3;

    for (int k0 = 0; k0 < KFULL; k0 += 64) {
        const int i0 = k0 >> 3;
        #pragma unroll
        for (int r = 0; r < 8; ++r) {
            const int row = brow0 + r * 16;
            const float4 v = *(const float4*)(coef + (size_t)(n0 + row) * KFULL + k0 + bcol * 4);
            bf16x4 pk;
            pk[0] = (short)f2bf(v.x); pk[1] = (short)f2bf(v.y);
            pk[2] = (short)f2bf(v.z); pk[3] = (short)f2bf(v.w);
            *(bf16x4*)&Bfs[row * LDK + bcol * 4] = pk;
        }
        #pragma unroll
        for (int r = 0; r < 4; ++r) {
            const int row = arow0 + r * 32;
            const float xv = x[(size_t)(m0 + row) * 1024 + i0 + acol];
            const float e  = __expf(2.0f * tr * xv);
            const float tt = 1.0f - 2.0f / (e + 1.0f);
            bf16x8 pk;
            float p = 1.0f;
            #pragma unroll
            for (int k = 0; k < 8; ++k) { pk[k] = (short)f2bf(p); p *= tt; }
            *(bf16x8*)&Afs[row * LDK + acol * 8] = pk;
        }
        __syncthreads();
        #pragma unroll
        for (int kk = 0; kk < 64; kk += 32) {
            bf16x8 a[4], b[4];
            #pragma unroll
            for (int i = 0; i < 4; i++)
                a[i] = *(const bf16x8*)&Afs[(wm + i * 16 + lrow) * LDK + kk + kq];
            #pragma unroll
            for (int j = 0; j < 4; j++)
                b[j] = *(const bf16x8*)&Bfs[(wn + j * 16 + lrow) * LDK + kk + kq];
            #pragma unroll
            for (int i = 0; i < 4; i++)
                #pragma unroll
                for (int j = 0; j < 4; j++)
                    acc[i][j] = __builtin_amdgcn_mfma_f32_16x16x32_bf16(a[i], b[j], acc[i][j], 0, 0, 0);
        }
        __syncthreads();
    }

    const int crow = (lane >> 4) * 4;
    const int ccol = lane & 15;
    #pragma unroll
    for (int i = 0; i < 4; i++) {
        #pragma unroll
        for (int j = 0; j < 4; j++) {
            const int m = m0 + wm + i * 16 + crow;
            const int n = n0 + wn + j * 16 + ccol;
            #pragma unroll
            for (int r = 0; r < 4; ++r)
                out[(size_t)(m + r) * 1024 + n] = acc[i][j][r];
        }
    }
}

extern "C" void kernel_launch(void* const* d_in, const int* in_sizes, int n_in,
                              void* d_out, int out_size, void* d_ws, size_t ws_size,
                              hipStream_t stream) {
    const float* x    = (const float*)d_in[0];
    const float* trp  = (const float*)d_in[1];
    const float* coef = (const float*)d_in[2];
    float* out = (float*)d_out;

    const size_t A_BYTES    = (size_t)8192 * KT * 2;   // 117,440,512
    const size_t COEF_BYTES = (size_t)1024 * KT * 2;   //  14,680,064
    const size_t BIAS_BYTES = 1024 * sizeof(float);

    if (ws_size >= A_BYTES + COEF_BYTES + BIAS_BYTES) {
        unsigned short* A_bf    = (unsigned short*)d_ws;
        unsigned short* coef_bf = (unsigned short*)((char*)d_ws + A_BYTES);
        float*          bias    = (float*)((char*)d_ws + A_BYTES + COEF_BYTES);

        prep<<<dim3(CVT_BLOCKS + TANH_BLOCKS), dim3(256), 0, stream>>>(
            x, trp, coef, coef_bf, A_bf, bias);
        gemm_bt<<<dim3(8192 / BM, 1024 / BN), dim3(256), 0, stream>>>(
            A_bf, coef_bf, bias, out);
    } else {
        taylor_gemm<<<dim3(8192 / BM, 1024 / BN), dim3(256), 0, stream>>>(x, trp, coef, out);
    }
}